// Round 1
// baseline (88.569 us; speedup 1.0000x reference)
//
#include <hip/hip_runtime.h>

// CZ ring on 13 wires = diagonal sign flip on the row index:
//   sign(row) = (-1)^( popcount(row & row>>1) + (bit12(row) & bit0(row)) )
//
// Output layout (verified in the previous session): harness compares d_out as
// one flat float32 array of out_size = 2*N elements, complex64 reference
// flattened PLANAR: [ real.ravel() | imag.ravel() ].
//
// Round 1 of this session:
//  - non-temporal stores (output is write-once, never re-read this dispatch;
//    keep MALL residency for the inputs, which ARE re-read every iteration)
//  - x4 unroll per thread (8 outstanding dwordx4 loads/thread instead of 2)

#define N_WIRES 13
#define BATCH_LOG2 12           // BATCH = 4096

typedef float f4 __attribute__((ext_vector_type(4)));

__device__ __forceinline__ float row_sign(unsigned row) {
    const unsigned adj    = row & (row >> 1);
    const unsigned parity = __popc(adj) + ((row >> (N_WIRES - 1)) & row & 1u);
    return (parity & 1u) ? -1.0f : 1.0f;
}

__global__ __launch_bounds__(256) void czring_kernel(
    const float* __restrict__ xr,
    const float* __restrict__ xi,
    float* __restrict__ out,
    unsigned n_complex,          // per-input element count (DIM*BATCH = 2^25)
    unsigned out_floats)         // harness out_size (expected 2*n_complex)
{
    const unsigned nthreads = gridDim.x * blockDim.x;
    const unsigned nquads   = n_complex >> 2;   // 4 floats per quad
    unsigned i = blockIdx.x * blockDim.x + threadIdx.x;

    if (out_floats >= 2u * n_complex) {
        // ---- fast path: full planar output, no bounds checks ----
        // main loop: 4 quads per thread per pass (coalesced at each k-step)
        for (; i + 3u * nthreads < nquads; i += 4u * nthreads) {
            unsigned base[4];
            f4 r[4], m[4];
            #pragma unroll
            for (int k = 0; k < 4; ++k) {
                base[k] = (i + (unsigned)k * nthreads) << 2;
                r[k] = *reinterpret_cast<const f4*>(xr + base[k]);
                m[k] = *reinterpret_cast<const f4*>(xi + base[k]);
            }
            #pragma unroll
            for (int k = 0; k < 4; ++k) {
                const float s = row_sign(base[k] >> BATCH_LOG2);
                f4 ro = s * r[k];
                f4 mo = s * m[k];
                __builtin_nontemporal_store(ro, reinterpret_cast<f4*>(out + base[k]));
                __builtin_nontemporal_store(mo, reinterpret_cast<f4*>(out + n_complex + base[k]));
            }
        }
        // remainder quads (not hit at the bench shape: nquads % (4*nthreads) == 0)
        for (; i < nquads; i += nthreads) {
            const unsigned base = i << 2;
            const float s = row_sign(base >> BATCH_LOG2);
            f4 r = *reinterpret_cast<const f4*>(xr + base);
            f4 m = *reinterpret_cast<const f4*>(xi + base);
            f4 ro = s * r;
            f4 mo = s * m;
            __builtin_nontemporal_store(ro, reinterpret_cast<f4*>(out + base));
            __builtin_nontemporal_store(mo, reinterpret_cast<f4*>(out + n_complex + base));
        }
    } else {
        // ---- defensive guarded path (out_size < 2*n_complex; never expected) ----
        for (; i < nquads; i += nthreads) {
            const unsigned base = i << 2;
            const float s = row_sign(base >> BATCH_LOG2);
            const f4 r = *reinterpret_cast<const f4*>(xr + base);
            const f4 m = *reinterpret_cast<const f4*>(xi + base);
            const unsigned oi = n_complex + base;
            #pragma unroll
            for (unsigned k = 0; k < 4; ++k) {
                if (base + k < out_floats) out[base + k] = s * r[k];
                if (oi   + k < out_floats) out[oi + k]   = s * m[k];
            }
        }
    }
}

extern "C" void kernel_launch(void* const* d_in, const int* in_sizes, int n_in,
                              void* d_out, int out_size, void* d_ws, size_t ws_size,
                              hipStream_t stream) {
    const float* xr = (const float*)d_in[0];
    const float* xi = (const float*)d_in[1];
    float* out = (float*)d_out;

    const unsigned n = (unsigned)in_sizes[0];         // 2^25 complex elements
    const unsigned nquads = n >> 2;

    const int threads = 256;
    // each thread covers 4 quads in the unrolled loop
    long long want = ((long long)nquads + threads * 4 - 1) / (threads * 4);
    int blocks = (int)want;
    if (blocks > 32768) blocks = 32768;               // grid-stride covers rest
    if (blocks < 1) blocks = 1;

    czring_kernel<<<blocks, threads, 0, stream>>>(xr, xi, out, n, (unsigned)out_size);
}

// Round 2
// 80.049 us; speedup vs baseline: 1.1064x; 1.1064x over previous
//
#include <hip/hip_runtime.h>

// CZ ring on 13 wires = diagonal sign flip on the row index:
//   sign(row) = (-1)^( popcount(row & row>>1) + (bit12(row) & bit0(row)) )
// (MSB-first adjacency maps onto LSB adjacency under bit reversal; wrap pair
// is symmetric.)
//
// Output layout (verified): harness compares d_out as a single flat float32
// array of out_size = 2*N elements, with the complex64 reference flattened
// PLANAR: [ real.ravel() | imag.ravel() ].
//
// Session round-2 note: this is the verified-best round-0 configuration,
// restored after round-1's A/B showed both NT stores and x4 unroll regress:
//  - NT stores: WRITE_SIZE 131072->138400 KB (less MALL write absorption),
//    FETCH unchanged -> no input-residency benefit. dur +10%.
//  - x4 unroll: 8 address streams/wave instead of 2; latency was never the
//    limiter (occupancy 68% already covers it).
// At 80.76 us this kernel moves 512 MiB app-level = 6.65 TB/s effective,
// ABOVE the 6.29 TB/s measured D2D copy ceiling (MALL absorbs ~50% of each
// stream; FETCH = WRITE = 128 MiB steady state). This is the streaming
// roofline for a copy-shaped op.

#define N_WIRES 13
#define BATCH_LOG2 12           // BATCH = 4096

__global__ __launch_bounds__(256) void czring_kernel(
    const float* __restrict__ xr,
    const float* __restrict__ xi,
    float* __restrict__ out,
    unsigned n_complex,          // per-input element count (DIM*BATCH = 2^25)
    unsigned out_floats)         // harness out_size (expected 2*n_complex)
{
    const unsigned nthreads = gridDim.x * blockDim.x;
    const unsigned nquads   = n_complex >> 2;   // 4 elements per thread-iter

    for (unsigned t = blockIdx.x * blockDim.x + threadIdx.x; t < nquads; t += nthreads) {
        const unsigned base = t << 2;           // element index (multiple of 4)

        // All 4 elements share one row (BATCH = 4096 is a multiple of 4).
        const unsigned row    = base >> BATCH_LOG2;
        const unsigned adj    = row & (row >> 1);
        const unsigned parity = __popc(adj) + ((row >> (N_WIRES - 1)) & row & 1u);
        const float sign = (parity & 1u) ? -1.0f : 1.0f;

        const float4 r = *reinterpret_cast<const float4*>(xr + base);
        const float4 m = *reinterpret_cast<const float4*>(xi + base);

        float4 ro, mo;
        ro.x = sign * r.x; ro.y = sign * r.y; ro.z = sign * r.z; ro.w = sign * r.w;
        mo.x = sign * m.x; mo.y = sign * m.y; mo.z = sign * m.z; mo.w = sign * m.w;

        // Planar stores: real block at [0, n), imag block at [n, 2n).
        const unsigned oi = n_complex + base;
        if (oi + 3u < out_floats) {
            *reinterpret_cast<float4*>(out + base) = ro;
            *reinterpret_cast<float4*>(out + oi)   = mo;
        } else {
            // Tail guard (only if out_size < 2*n_complex — defensive).
            const float rv[4] = {ro.x, ro.y, ro.z, ro.w};
            const float mv[4] = {mo.x, mo.y, mo.z, mo.w};
            #pragma unroll
            for (unsigned k = 0; k < 4; ++k) {
                if (base + k < out_floats) out[base + k] = rv[k];
                if (oi   + k < out_floats) out[oi + k]   = mv[k];
            }
        }
    }
}

extern "C" void kernel_launch(void* const* d_in, const int* in_sizes, int n_in,
                              void* d_out, int out_size, void* d_ws, size_t ws_size,
                              hipStream_t stream) {
    const float* xr = (const float*)d_in[0];
    const float* xi = (const float*)d_in[1];
    float* out = (float*)d_out;

    const unsigned n = (unsigned)in_sizes[0];         // 2^25 complex elements
    const unsigned nquads = n >> 2;

    const int threads = 256;
    int blocks = (int)((nquads + threads - 1) / threads);
    if (blocks > 32768) blocks = 32768;               // grid-stride covers rest
    if (blocks < 1) blocks = 1;

    czring_kernel<<<blocks, threads, 0, stream>>>(xr, xi, out, n, (unsigned)out_size);
}